// Round 10
// baseline (209.387 us; speedup 1.0000x reference)
//
#include <hip/hip_runtime.h>
#include <math.h>

#define NF 256
#define NH 128
#define NC 16
#define NB 391      // buckets of 128 nodes: 391*128 = 50048 >= 50000
#define NBLK 128    // binning blocks (must equal passA/passB grid)

typedef __attribute__((ext_vector_type(8))) short bf16x8;
typedef __attribute__((ext_vector_type(4))) float f32x4;

// ---- bf16 helpers ---------------------------------------------------------
__device__ __forceinline__ unsigned f2b(float f) {            // RNE to bf16 bits
    unsigned u = __float_as_uint(f);
    return (u + 0x7FFFu + ((u >> 16) & 1u)) >> 16;
}
__device__ __forceinline__ unsigned pack2(float a, float b) { // RNE pair
    return f2b(a) | (f2b(b) << 16);
}
__device__ __forceinline__ unsigned packt(float a, float b) { // truncate pair (MFMA inputs)
    return (__float_as_uint(a) >> 16) | (__float_as_uint(b) & 0xFFFF0000u);
}
__device__ __forceinline__ float blo(unsigned u) { return __uint_as_float(u << 16); }
__device__ __forceinline__ float bhi(unsigned u) { return __uint_as_float(u & 0xFFFF0000u); }

// ---------------------------------------------------------------------------
// passA: per-block bucket histogram (LDS atomics only; coalesced row write).
__global__ void passA_kernel(const int* __restrict__ dst, int* __restrict__ hist, int E) {
    __shared__ int h[NB];
    for (int i = threadIdx.x; i < NB; i += 256) h[i] = 0;
    __syncthreads();
    int b = blockIdx.x;
    int e0 = (int)((long long)b * E / NBLK), e1 = (int)((long long)(b + 1) * E / NBLK);
    for (int e = e0 + (int)threadIdx.x; e < e1; e += 256)
        atomicAdd(&h[dst[e] >> 7], 1);
    __syncthreads();
    for (int i = threadIdx.x; i < NB; i += 256) hist[b * NB + i] = h[i];
}

// scanR: bucketsum[k] = sum over blocks of hist[b][k].
__global__ void scanR_kernel(const int* __restrict__ hist, int* __restrict__ bsum) {
    __shared__ int sm[NBLK];
    int k = blockIdx.x, t = threadIdx.x;
    sm[t] = hist[t * NB + k];
    __syncthreads();
    for (int off = NBLK / 2; off > 0; off >>= 1) {
        if (t < off) sm[t] += sm[t + off];
        __syncthreads();
    }
    if (t == 0) bsum[k] = sm[0];
}

// scanB: exclusive scan of NB bucket sums -> bbase[NB+1]; rowptr[N]=E.
__global__ void scanB_kernel(const int* __restrict__ bsum, int* __restrict__ bbase,
                             int* __restrict__ rowptr, int N, int E) {
    __shared__ int sm[512];
    int t = threadIdx.x;
    int v = (t < NB) ? bsum[t] : 0;
    sm[t] = v;
    __syncthreads();
    for (int off = 1; off < 512; off <<= 1) {
        int u = (t >= off) ? sm[t - off] : 0;
        __syncthreads();
        sm[t] += u;
        __syncthreads();
    }
    if (t < NB) bbase[t] = sm[t] - v;
    if (t == 0) { bbase[NB] = E; rowptr[N] = E; }
}

// scanC: per-bucket column exclusive scan across blocks + bucket base
// (overwrites hist with each block's exact output offset for that bucket).
__global__ void scanC_kernel(int* __restrict__ hist, const int* __restrict__ bbase) {
    __shared__ int sm[NBLK];
    int k = blockIdx.x, t = threadIdx.x;
    int v = hist[t * NB + k];
    sm[t] = v;
    __syncthreads();
    for (int off = 1; off < NBLK; off <<= 1) {
        int u = (t >= off) ? sm[t - off] : 0;
        __syncthreads();
        sm[t] += u;
        __syncthreads();
    }
    hist[t * NB + k] = bbase[k] + sm[t] - v;
}

// passB: binned scatter to bucket-sorted edge words. LDS cursors hold GLOBAL
// slots (disjoint per block, exact) -> deterministic ranges, ~32-entry
// contiguous runs per bucket (lines fill fully before eviction).
__global__ void passB_kernel(const int* __restrict__ src, const int* __restrict__ dst,
                             const int* __restrict__ hist, unsigned* __restrict__ ebuf,
                             int E) {
    __shared__ int cur[NB];
    int b = blockIdx.x;
    for (int i = threadIdx.x; i < NB; i += 256) cur[i] = hist[b * NB + i];
    __syncthreads();
    int e0 = (int)((long long)b * E / NBLK), e1 = (int)((long long)(b + 1) * E / NBLK);
    for (int e = e0 + (int)threadIdx.x; e < e1; e += 256) {
        int d = dst[e];
        int pos = atomicAdd(&cur[d >> 7], 1);
        ebuf[pos] = ((unsigned)d << 16) | (unsigned)src[e];
    }
}

// passC: one block per bucket: per-node histogram -> rowptr/dis, then in-bucket
// scatter to final dst-sorted u16 colidx (8KB window, L2-hot).
__global__ void passC_kernel(const unsigned* __restrict__ ebuf, const int* __restrict__ bbase,
                             int* __restrict__ rowptr, float* __restrict__ dis,
                             unsigned short* __restrict__ colidx, int N) {
    __shared__ int h[128];
    __shared__ int s2[128];
    __shared__ int curp[128];
    int k = blockIdx.x, t = threadIdx.x;
    if (t < 128) h[t] = 0;
    __syncthreads();
    int e0 = bbase[k], e1 = bbase[k + 1];
    for (int e = e0 + t; e < e1; e += 256)
        atomicAdd(&h[(ebuf[e] >> 16) & 127], 1);
    __syncthreads();
    int v = (t < 128) ? h[t] : 0;
    if (t < 128) s2[t] = v;
    __syncthreads();
    for (int off = 1; off < 128; off <<= 1) {
        int u = (t < 128 && t >= off) ? s2[t - off] : 0;
        __syncthreads();
        if (t < 128) s2[t] += u;
        __syncthreads();
    }
    if (t < 128) {
        int node = k * 128 + t;
        int r = e0 + s2[t] - v;             // exclusive prefix -> first slot of node
        if (node < N) {
            rowptr[node] = r;
            dis[node] = rsqrtf((float)(v + 1));
        }
        curp[t] = r;
    }
    __syncthreads();
    for (int e = e0 + t; e < e1; e += 256) {
        unsigned w = ebuf[e];
        int dl = (w >> 16) & 127;
        int pos = atomicAdd(&curp[dl], 1);
        colidx[pos] = (unsigned short)(w & 0xFFFFu);
    }
}

// ---------------------------------------------------------------------------
// h1 = dis * (x @ W1) via MFMA bf16.  Stored SLAB-MAJOR: slab p (cols
// [32p,32p+32)) is h1T[p][node][32 ushort] so each agg pass gathers a 3.2MB
// (per-XCD-L2-resident) slab.  col = nt*16+lrow -> slab nt>>1, off
// (nt&1)*16+lrow.  W1 staged once/block into LDS bf16-transposed (64KB).
__global__ __launch_bounds__(256) void gemm1_mfma_kernel(
    const float* __restrict__ x, const float* __restrict__ W1,
    const float* __restrict__ dis, unsigned short* __restrict__ h1us, int N) {
    __shared__ char sW1T[65536];
    int tid = threadIdx.x;
    for (int idx = tid; idx < NF * NH; idx += 256) {
        int k = idx >> 7, n = idx & 127;
        unsigned short h = (unsigned short)f2b(W1[idx]);
        *(unsigned short*)(sW1T + n * 512 + ((k * 2) ^ ((n & 7) << 4))) = h;
    }
    __syncthreads();

    int wid = tid >> 6, lane = tid & 63;
    int lrow = lane & 15, lk = lane >> 4;      // A-frag: row=lane&15, k-chunk=lane>>4
    int rb = blockIdx.x * 64 + wid * 16;
    int ra = rb + lrow;
    int rc = ra < N ? ra : N - 1;              // clamp (last block); extras discarded
    const float* xr = x + (size_t)rc * NF + lk * 8;

    f32x4 acc[8];
#pragma unroll
    for (int t = 0; t < 8; ++t) acc[t] = (f32x4){0.f, 0.f, 0.f, 0.f};

#pragma unroll
    for (int kk = 0; kk < 8; ++kk) {
        float4 lo = *reinterpret_cast<const float4*>(xr + kk * 32);
        float4 hi = *reinterpret_cast<const float4*>(xr + kk * 32 + 4);
        union { unsigned u[4]; bf16x8 v; } av;
        av.u[0] = packt(lo.x, lo.y);
        av.u[1] = packt(lo.z, lo.w);
        av.u[2] = packt(hi.x, hi.y);
        av.u[3] = packt(hi.z, hi.w);
        int kbyte = kk * 64 + lk * 16;
#pragma unroll
        for (int nt = 0; nt < 8; ++nt) {
            int n = nt * 16 + lrow;            // B-frag: col=lane&15, k-chunk=lane>>4
            bf16x8 bv = *(const bf16x8*)(sW1T + n * 512 + (kbyte ^ ((n & 7) << 4)));
            acc[nt] = __builtin_amdgcn_mfma_f32_16x16x32_bf16(av.v, bv, acc[nt], 0, 0, 0);
        }
    }
    // C/D layout (verified m89): col = lane&15, row_in_tile = (lane>>4)*4 + r
    int crow0 = rb + lk * 4;
#pragma unroll
    for (int r = 0; r < 4; ++r) {
        int row = crow0 + r;
        if (row < N) {
            float dr = dis[row];
#pragma unroll
            for (int nt = 0; nt < 8; ++nt) {
                size_t a = ((size_t)(nt >> 1) * N + row) * 32 + ((nt & 1) * 16 + lrow);
                h1us[a] = (unsigned short)f2b(acc[nt][r] * dr);
            }
        }
    }
}

// ---------------------------------------------------------------------------
// Agg pass p: for every node, sum self + neighbors over slab p (32 features,
// 16 u32/node).  16 lanes per node; all CUs gather from the SAME 3.2MB slab
// -> per-XCD L2 resident.  Output aggT[p][node][16 u32] bf16-packed.
__global__ __launch_bounds__(256) void aggpass_kernel(
    const int* __restrict__ rowptr, const unsigned short* __restrict__ colidx,
    const unsigned* __restrict__ h1T, unsigned* __restrict__ aggT, int N, int p) {
    int i = blockIdx.x * 16 + (threadIdx.x >> 4);
    if (i >= N) return;
    int l = threadIdx.x & 15;
    const unsigned* slab = h1T + (size_t)p * N * 16;
    unsigned sv = slab[(size_t)i * 16 + l];             // self-loop
    float ax = blo(sv), ay = bhi(sv);
    int e = rowptr[i], e1 = rowptr[i + 1];
    for (; e + 4 <= e1; e += 4) {
        int a = colidx[e], b = colidx[e + 1], c = colidx[e + 2], d = colidx[e + 3];
        unsigned va = slab[(size_t)a * 16 + l];
        unsigned vb = slab[(size_t)b * 16 + l];
        unsigned vc = slab[(size_t)c * 16 + l];
        unsigned vd = slab[(size_t)d * 16 + l];
        ax += (blo(va) + blo(vb)) + (blo(vc) + blo(vd));
        ay += (bhi(va) + bhi(vb)) + (bhi(vc) + bhi(vd));
    }
    for (; e < e1; ++e) {
        unsigned v = slab[(size_t)colidx[e] * 16 + l];
        ax += blo(v); ay += bhi(v);
    }
    aggT[(size_t)p * N * 16 + (size_t)i * 16 + l] = pack2(ax, ay);
}

// ---------------------------------------------------------------------------
// ReLU + bias + GEMM2 from aggT.  One wave per node (4 nodes/block).
// Lane l: slab p=l>>4, u32 (l&15) -> cols c0 = 32p + 2*(l&15), c0+1.
__global__ __launch_bounds__(256) void relu_gemm2_kernel(
    const unsigned* __restrict__ aggT, const float* __restrict__ dis,
    const float* __restrict__ b1, const float* __restrict__ W2,
    unsigned* __restrict__ h2sb, int N) {
    __shared__ float sW2[NH * NC];   // 8 KB
    __shared__ float srow[4][NH];    // 2 KB
    int tid = threadIdx.x;
    for (int k = tid; k < NH * NC; k += 256) sW2[k] = W2[k];
    __syncthreads();

    int wid = tid >> 6, lane = tid & 63;
    int i = blockIdx.x * 4 + wid;
    if (i >= N) return;
    int p = lane >> 4, l16 = lane & 15;
    unsigned v = aggT[((size_t)p * N + i) * 16 + l16];
    float di = dis[i];
    int c0 = p * 32 + l16 * 2;
    srow[wid][c0]     = fmaxf(di * blo(v) + b1[c0], 0.f);
    srow[wid][c0 + 1] = fmaxf(di * bhi(v) + b1[c0 + 1], 0.f);
    int j = lane & 15, q = lane >> 4;
    const float* rw = srow[wid];
    float pacc = 0.f;
#pragma unroll
    for (int cc = 0; cc < 32; ++cc) {
        int c = q * 32 + cc;
        pacc += rw[c] * sW2[c * NC + j];
    }
    pacc += __shfl_xor(pacc, 16, 64);
    pacc += __shfl_xor(pacc, 32, 64);
    float dp = di * pacc;
    float plo = __shfl(dp, (lane << 1) & 63, 64);
    float phi = __shfl(dp, ((lane << 1) | 1) & 63, 64);
    if (lane < 8) h2sb[(size_t)i * 8 + lane] = pack2(plo, phi);
}

// ---------------------------------------------------------------------------
// Layer 2 pull + bias + log_softmax.  8 lanes/node (2 classes per lane).
// h2sb is 1.6MB -> already per-XCD-L2-resident.
__global__ void layer2_kernel(const int* __restrict__ rowptr, const unsigned short* __restrict__ colidx,
                              const unsigned* __restrict__ h2sb, const float* __restrict__ dis,
                              const float* __restrict__ b2, float* __restrict__ out, int N) {
    int t = blockIdx.x * 256 + threadIdx.x;
    int i = t >> 3;
    if (i >= N) return;
    int j2 = t & 7;
    int e = rowptr[i], e1 = rowptr[i + 1];
    unsigned sv = h2sb[(size_t)i * 8 + j2];             // self-loop
    float ax = blo(sv), ay = bhi(sv);
    for (; e + 4 <= e1; e += 4) {
        int a = colidx[e], b = colidx[e + 1], c = colidx[e + 2], d = colidx[e + 3];
        unsigned ga = h2sb[(size_t)a * 8 + j2];
        unsigned gb = h2sb[(size_t)b * 8 + j2];
        unsigned gc = h2sb[(size_t)c * 8 + j2];
        unsigned gd = h2sb[(size_t)d * 8 + j2];
        ax += (blo(ga) + blo(gb)) + (blo(gc) + blo(gd));
        ay += (bhi(ga) + bhi(gb)) + (bhi(gc) + bhi(gd));
    }
    for (; e < e1; ++e) {
        unsigned g = h2sb[(size_t)colidx[e] * 8 + j2];
        ax += blo(g); ay += bhi(g);
    }
    float di = dis[i];
    float l0 = di * ax + b2[2 * j2];
    float l1 = di * ay + b2[2 * j2 + 1];
    float m = fmaxf(l0, l1);
    m = fmaxf(m, __shfl_xor(m, 1, 64));
    m = fmaxf(m, __shfl_xor(m, 2, 64));
    m = fmaxf(m, __shfl_xor(m, 4, 64));
    float s = __expf(l0 - m) + __expf(l1 - m);
    s += __shfl_xor(s, 1, 64);
    s += __shfl_xor(s, 2, 64);
    s += __shfl_xor(s, 4, 64);
    float lse = m + __logf(s);
    float2 o = make_float2(l0 - lse, l1 - lse);
    *reinterpret_cast<float2*>(out + (size_t)i * NC + 2 * j2) = o;
}

// ---------------------------------------------------------------------------
extern "C" void kernel_launch(void* const* d_in, const int* in_sizes, int n_in,
                              void* d_out, int out_size, void* d_ws, size_t ws_size,
                              hipStream_t stream) {
    const float* x  = (const float*)d_in[0];
    const int*   ei = (const int*)d_in[1];
    const float* W1 = (const float*)d_in[2];
    const float* b1 = (const float*)d_in[3];
    const float* W2 = (const float*)d_in[4];
    const float* b2 = (const float*)d_in[5];
    float* out = (float*)d_out;

    const int N = in_sizes[0] / NF;   // 50000
    const int E = in_sizes[1] / 2;    // 1600000
    const int* src = ei;
    const int* dst = ei + E;

    // workspace layout (~38 MB); every consumed cell rewritten per call -> no memsets
    unsigned*       h1T    = (unsigned*)d_ws;                  // N*64 u32 (12.8 MB, 4 slabs)
    unsigned*       aggT   = h1T + (size_t)N * 64;             // N*64 u32 (12.8 MB, 4 slabs)
    unsigned*       h2sb   = aggT + (size_t)N * 64;            // N*8  u32 (1.6 MB)
    float*          dis    = (float*)(h2sb + (size_t)N * 8);   // N
    int*            rowptr = (int*)(dis + N);                  // N+1
    int*            hist   = rowptr + N + 1;                   // NBLK*NB (200 KB)
    int*            bsum   = hist + NBLK * NB;                 // NB
    int*            bbase  = bsum + NB;                        // NB+1
    unsigned*       ebuf   = (unsigned*)(bbase + NB + 1);      // E u32 (6.4 MB)
    unsigned short* colidx = (unsigned short*)(ebuf + E);      // E u16 (3.2 MB)

    passA_kernel<<<NBLK, 256, 0, stream>>>(dst, hist, E);
    scanR_kernel<<<NB, NBLK, 0, stream>>>(hist, bsum);
    scanB_kernel<<<1, 512, 0, stream>>>(bsum, bbase, rowptr, N, E);
    scanC_kernel<<<NB, NBLK, 0, stream>>>(hist, bbase);
    passB_kernel<<<NBLK, 256, 0, stream>>>(src, dst, hist, ebuf, E);
    passC_kernel<<<NB, 256, 0, stream>>>(ebuf, bbase, rowptr, dis, colidx, N);

    gemm1_mfma_kernel<<<(N + 63) / 64, 256, 0, stream>>>(x, W1, dis,
                                                         (unsigned short*)h1T, N);

    for (int p = 0; p < 4; ++p)
        aggpass_kernel<<<(N + 15) / 16, 256, 0, stream>>>(rowptr, colidx, h1T, aggT, N, p);

    relu_gemm2_kernel<<<(N + 3) / 4, 256, 0, stream>>>(aggT, dis, b1, W2, h2sb, N);

    layer2_kernel<<<((size_t)N * 8 + 255) / 256, 256, 0, stream>>>(rowptr, colidx, h2sb, dis, b2, out, N);
}

// Round 11
// 197.226 us; speedup vs baseline: 1.0617x; 1.0617x over previous
//
#include <hip/hip_runtime.h>
#include <math.h>

#define NF 256
#define NH 128
#define NC 16
#define NB 391      // buckets of 128 nodes: 391*128 = 50048 >= 50000
#define NBLK 512    // binning blocks (passA/passB grid; scanR/scanC block dim)

typedef __attribute__((ext_vector_type(8))) short bf16x8;
typedef __attribute__((ext_vector_type(4))) float f32x4;

// ---- bf16 helpers ---------------------------------------------------------
__device__ __forceinline__ unsigned f2b(float f) {            // RNE to bf16 bits
    unsigned u = __float_as_uint(f);
    return (u + 0x7FFFu + ((u >> 16) & 1u)) >> 16;
}
__device__ __forceinline__ unsigned pack2(float a, float b) { // RNE pair
    return f2b(a) | (f2b(b) << 16);
}
__device__ __forceinline__ unsigned packt(float a, float b) { // truncate pair (MFMA inputs)
    return (__float_as_uint(a) >> 16) | (__float_as_uint(b) & 0xFFFF0000u);
}
__device__ __forceinline__ float blo(unsigned u) { return __uint_as_float(u << 16); }
__device__ __forceinline__ float bhi(unsigned u) { return __uint_as_float(u & 0xFFFF0000u); }

// ---------------------------------------------------------------------------
// passA: per-block bucket histogram (LDS atomics only; coalesced row write).
__global__ void passA_kernel(const int* __restrict__ dst, int* __restrict__ hist, int E) {
    __shared__ int h[NB];
    for (int i = threadIdx.x; i < NB; i += 256) h[i] = 0;
    __syncthreads();
    int b = blockIdx.x;
    int e0 = (int)((long long)b * E / NBLK), e1 = (int)((long long)(b + 1) * E / NBLK);
    for (int e = e0 + (int)threadIdx.x; e < e1; e += 256)
        atomicAdd(&h[dst[e] >> 7], 1);
    __syncthreads();
    for (int i = threadIdx.x; i < NB; i += 256) hist[b * NB + i] = h[i];
}

// scanR: bucketsum[k] = sum over blocks of hist[b][k].  (NBLK threads)
__global__ void scanR_kernel(const int* __restrict__ hist, int* __restrict__ bsum) {
    __shared__ int sm[NBLK];
    int k = blockIdx.x, t = threadIdx.x;
    sm[t] = hist[t * NB + k];
    __syncthreads();
    for (int off = NBLK / 2; off > 0; off >>= 1) {
        if (t < off) sm[t] += sm[t + off];
        __syncthreads();
    }
    if (t == 0) bsum[k] = sm[0];
}

// scanB: exclusive scan of NB bucket sums -> bbase[NB+1]; rowptr[N]=E.
__global__ void scanB_kernel(const int* __restrict__ bsum, int* __restrict__ bbase,
                             int* __restrict__ rowptr, int N, int E) {
    __shared__ int sm[512];
    int t = threadIdx.x;
    int v = (t < NB) ? bsum[t] : 0;
    sm[t] = v;
    __syncthreads();
    for (int off = 1; off < 512; off <<= 1) {
        int u = (t >= off) ? sm[t - off] : 0;
        __syncthreads();
        sm[t] += u;
        __syncthreads();
    }
    if (t < NB) bbase[t] = sm[t] - v;
    if (t == 0) { bbase[NB] = E; rowptr[N] = E; }
}

// scanC: per-bucket column exclusive scan across blocks + bucket base
// (overwrites hist with each block's exact output offset).  (NBLK threads)
__global__ void scanC_kernel(int* __restrict__ hist, const int* __restrict__ bbase) {
    __shared__ int sm[NBLK];
    int k = blockIdx.x, t = threadIdx.x;
    int v = hist[t * NB + k];
    sm[t] = v;
    __syncthreads();
    for (int off = 1; off < NBLK; off <<= 1) {
        int u = (t >= off) ? sm[t - off] : 0;
        __syncthreads();
        sm[t] += u;
        __syncthreads();
    }
    hist[t * NB + k] = bbase[k] + sm[t] - v;
}

// passB: binned scatter to bucket-sorted edge words. LDS cursors hold GLOBAL
// slots (disjoint per block, exact) -> deterministic ranges, contiguous runs.
__global__ void passB_kernel(const int* __restrict__ src, const int* __restrict__ dst,
                             const int* __restrict__ hist, unsigned* __restrict__ ebuf,
                             int E) {
    __shared__ int cur[NB];
    int b = blockIdx.x;
    for (int i = threadIdx.x; i < NB; i += 256) cur[i] = hist[b * NB + i];
    __syncthreads();
    int e0 = (int)((long long)b * E / NBLK), e1 = (int)((long long)(b + 1) * E / NBLK);
    for (int e = e0 + (int)threadIdx.x; e < e1; e += 256) {
        int d = dst[e];
        int pos = atomicAdd(&cur[d >> 7], 1);
        ebuf[pos] = ((unsigned)d << 16) | (unsigned)src[e];
    }
}

// passC: one block per bucket: per-node histogram -> rowptr/dis, then in-bucket
// scatter to final dst-sorted u16 colidx (8KB window, L2-hot).
__global__ void passC_kernel(const unsigned* __restrict__ ebuf, const int* __restrict__ bbase,
                             int* __restrict__ rowptr, float* __restrict__ dis,
                             unsigned short* __restrict__ colidx, int N) {
    __shared__ int h[128];
    __shared__ int s2[128];
    __shared__ int curp[128];
    int k = blockIdx.x, t = threadIdx.x;
    if (t < 128) h[t] = 0;
    __syncthreads();
    int e0 = bbase[k], e1 = bbase[k + 1];
    for (int e = e0 + t; e < e1; e += 256)
        atomicAdd(&h[(ebuf[e] >> 16) & 127], 1);
    __syncthreads();
    int v = (t < 128) ? h[t] : 0;
    if (t < 128) s2[t] = v;
    __syncthreads();
    for (int off = 1; off < 128; off <<= 1) {
        int u = (t < 128 && t >= off) ? s2[t - off] : 0;
        __syncthreads();
        if (t < 128) s2[t] += u;
        __syncthreads();
    }
    if (t < 128) {
        int node = k * 128 + t;
        int r = e0 + s2[t] - v;             // exclusive prefix -> first slot of node
        if (node < N) {
            rowptr[node] = r;
            dis[node] = rsqrtf((float)(v + 1));
        }
        curp[t] = r;
    }
    __syncthreads();
    for (int e = e0 + t; e < e1; e += 256) {
        unsigned w = ebuf[e];
        int dl = (w >> 16) & 127;
        int pos = atomicAdd(&curp[dl], 1);
        colidx[pos] = (unsigned short)(w & 0xFFFFu);
    }
}

// ---------------------------------------------------------------------------
// W1T[n][k] = bf16(W1[k][n]).  128x256 u16 (64KB) -> L2-resident B operand.
// Reads scattered (stride 512B, L2-served), writes coalesced u16 runs.
__global__ void w1t_kernel(const float* __restrict__ W1, unsigned short* __restrict__ W1T) {
    int idx = blockIdx.x * 256 + threadIdx.x;   // 128 blocks x 256 = 32768
    int n = idx >> 8, k = idx & 255;
    W1T[n * 256 + k] = (unsigned short)f2b(W1[(size_t)k * NH + n]);
}

// ---------------------------------------------------------------------------
// h1 = dis * (x @ W1) via MFMA bf16, NO LDS: B-fragments loaded directly from
// global W1T (64KB, L2/L1-resident; 16B/lane contiguous).  Stored SLAB-MAJOR:
// slab p holds cols [32p,32p+32) as h1T[p][node][32 ushort] for the agg passes.
// 64 rows/block, 4 waves x 16 rows; per wave 8 N-tiles x 8 K-steps.
__global__ __launch_bounds__(256) void gemm1_mfma_kernel(
    const float* __restrict__ x, const unsigned short* __restrict__ W1T,
    const float* __restrict__ dis, unsigned short* __restrict__ h1us, int N) {
    int tid = threadIdx.x;
    int wid = tid >> 6, lane = tid & 63;
    int lrow = lane & 15, lk = lane >> 4;      // A-frag: row=lane&15, k-chunk=lane>>4
    int rb = blockIdx.x * 64 + wid * 16;
    int ra = rb + lrow;
    int rc = ra < N ? ra : N - 1;              // clamp (last block); extras discarded
    const float* xr = x + (size_t)rc * NF + lk * 8;

    f32x4 acc[8];
#pragma unroll
    for (int t = 0; t < 8; ++t) acc[t] = (f32x4){0.f, 0.f, 0.f, 0.f};

#pragma unroll
    for (int kk = 0; kk < 8; ++kk) {
        float4 lo = *reinterpret_cast<const float4*>(xr + kk * 32);
        float4 hi = *reinterpret_cast<const float4*>(xr + kk * 32 + 4);
        union { unsigned u[4]; bf16x8 v; } av;
        av.u[0] = packt(lo.x, lo.y);
        av.u[1] = packt(lo.z, lo.w);
        av.u[2] = packt(hi.x, hi.y);
        av.u[3] = packt(hi.z, hi.w);
#pragma unroll
        for (int nt = 0; nt < 8; ++nt) {
            int n = nt * 16 + lrow;            // B-frag: col=lane&15, k-chunk=lane>>4
            bf16x8 bv = *(const bf16x8*)(W1T + (size_t)n * 256 + kk * 32 + lk * 8);
            acc[nt] = __builtin_amdgcn_mfma_f32_16x16x32_bf16(av.v, bv, acc[nt], 0, 0, 0);
        }
    }
    // C/D layout (verified m89): col = lane&15, row_in_tile = (lane>>4)*4 + r
    int crow0 = rb + lk * 4;
#pragma unroll
    for (int r = 0; r < 4; ++r) {
        int row = crow0 + r;
        if (row < N) {
            float dr = dis[row];
#pragma unroll
            for (int nt = 0; nt < 8; ++nt) {
                size_t a = ((size_t)(nt >> 1) * N + row) * 32 + ((nt & 1) * 16 + lrow);
                h1us[a] = (unsigned short)f2b(acc[nt][r] * dr);
            }
        }
    }
}

// ---------------------------------------------------------------------------
// Agg pass p: for every node, sum self + neighbors over slab p (32 features,
// 16 u32/node).  16 lanes per node; all CUs gather from the SAME 3.2MB slab
// -> per-XCD L2 resident.  Output aggT[p][node][16 u32] bf16-packed.
__global__ __launch_bounds__(256) void aggpass_kernel(
    const int* __restrict__ rowptr, const unsigned short* __restrict__ colidx,
    const unsigned* __restrict__ h1T, unsigned* __restrict__ aggT, int N, int p) {
    int i = blockIdx.x * 16 + (threadIdx.x >> 4);
    if (i >= N) return;
    int l = threadIdx.x & 15;
    const unsigned* slab = h1T + (size_t)p * N * 16;
    unsigned sv = slab[(size_t)i * 16 + l];             // self-loop
    float ax = blo(sv), ay = bhi(sv);
    int e = rowptr[i], e1 = rowptr[i + 1];
    for (; e + 4 <= e1; e += 4) {
        int a = colidx[e], b = colidx[e + 1], c = colidx[e + 2], d = colidx[e + 3];
        unsigned va = slab[(size_t)a * 16 + l];
        unsigned vb = slab[(size_t)b * 16 + l];
        unsigned vc = slab[(size_t)c * 16 + l];
        unsigned vd = slab[(size_t)d * 16 + l];
        ax += (blo(va) + blo(vb)) + (blo(vc) + blo(vd));
        ay += (bhi(va) + bhi(vb)) + (bhi(vc) + bhi(vd));
    }
    for (; e < e1; ++e) {
        unsigned v = slab[(size_t)colidx[e] * 16 + l];
        ax += blo(v); ay += bhi(v);
    }
    aggT[(size_t)p * N * 16 + (size_t)i * 16 + l] = pack2(ax, ay);
}

// ---------------------------------------------------------------------------
// ReLU + bias + GEMM2 from aggT.  One wave per node (4 nodes/block).
// Lane l: slab p=l>>4, u32 (l&15) -> cols c0 = 32p + 2*(l&15), c0+1.
__global__ __launch_bounds__(256) void relu_gemm2_kernel(
    const unsigned* __restrict__ aggT, const float* __restrict__ dis,
    const float* __restrict__ b1, const float* __restrict__ W2,
    unsigned* __restrict__ h2sb, int N) {
    __shared__ float sW2[NH * NC];   // 8 KB
    __shared__ float srow[4][NH];    // 2 KB
    int tid = threadIdx.x;
    for (int k = tid; k < NH * NC; k += 256) sW2[k] = W2[k];
    __syncthreads();

    int wid = tid >> 6, lane = tid & 63;
    int i = blockIdx.x * 4 + wid;
    if (i >= N) return;
    int p = lane >> 4, l16 = lane & 15;
    unsigned v = aggT[((size_t)p * N + i) * 16 + l16];
    float di = dis[i];
    int c0 = p * 32 + l16 * 2;
    srow[wid][c0]     = fmaxf(di * blo(v) + b1[c0], 0.f);
    srow[wid][c0 + 1] = fmaxf(di * bhi(v) + b1[c0 + 1], 0.f);
    int j = lane & 15, q = lane >> 4;
    const float* rw = srow[wid];
    float pacc = 0.f;
#pragma unroll
    for (int cc = 0; cc < 32; ++cc) {
        int c = q * 32 + cc;
        pacc += rw[c] * sW2[c * NC + j];
    }
    pacc += __shfl_xor(pacc, 16, 64);
    pacc += __shfl_xor(pacc, 32, 64);
    float dp = di * pacc;
    float plo = __shfl(dp, (lane << 1) & 63, 64);
    float phi = __shfl(dp, ((lane << 1) | 1) & 63, 64);
    if (lane < 8) h2sb[(size_t)i * 8 + lane] = pack2(plo, phi);
}

// ---------------------------------------------------------------------------
// Layer 2 pull + bias + log_softmax.  8 lanes/node (2 classes per lane).
// h2sb is 1.6MB -> already per-XCD-L2-resident.
__global__ void layer2_kernel(const int* __restrict__ rowptr, const unsigned short* __restrict__ colidx,
                              const unsigned* __restrict__ h2sb, const float* __restrict__ dis,
                              const float* __restrict__ b2, float* __restrict__ out, int N) {
    int t = blockIdx.x * 256 + threadIdx.x;
    int i = t >> 3;
    if (i >= N) return;
    int j2 = t & 7;
    int e = rowptr[i], e1 = rowptr[i + 1];
    unsigned sv = h2sb[(size_t)i * 8 + j2];             // self-loop
    float ax = blo(sv), ay = bhi(sv);
    for (; e + 4 <= e1; e += 4) {
        int a = colidx[e], b = colidx[e + 1], c = colidx[e + 2], d = colidx[e + 3];
        unsigned ga = h2sb[(size_t)a * 8 + j2];
        unsigned gb = h2sb[(size_t)b * 8 + j2];
        unsigned gc = h2sb[(size_t)c * 8 + j2];
        unsigned gd = h2sb[(size_t)d * 8 + j2];
        ax += (blo(ga) + blo(gb)) + (blo(gc) + blo(gd));
        ay += (bhi(ga) + bhi(gb)) + (bhi(gc) + bhi(gd));
    }
    for (; e < e1; ++e) {
        unsigned g = h2sb[(size_t)colidx[e] * 8 + j2];
        ax += blo(g); ay += bhi(g);
    }
    float di = dis[i];
    float l0 = di * ax + b2[2 * j2];
    float l1 = di * ay + b2[2 * j2 + 1];
    float m = fmaxf(l0, l1);
    m = fmaxf(m, __shfl_xor(m, 1, 64));
    m = fmaxf(m, __shfl_xor(m, 2, 64));
    m = fmaxf(m, __shfl_xor(m, 4, 64));
    float s = __expf(l0 - m) + __expf(l1 - m);
    s += __shfl_xor(s, 1, 64);
    s += __shfl_xor(s, 2, 64);
    s += __shfl_xor(s, 4, 64);
    float lse = m + __logf(s);
    float2 o = make_float2(l0 - lse, l1 - lse);
    *reinterpret_cast<float2*>(out + (size_t)i * NC + 2 * j2) = o;
}

// ---------------------------------------------------------------------------
extern "C" void kernel_launch(void* const* d_in, const int* in_sizes, int n_in,
                              void* d_out, int out_size, void* d_ws, size_t ws_size,
                              hipStream_t stream) {
    const float* x  = (const float*)d_in[0];
    const int*   ei = (const int*)d_in[1];
    const float* W1 = (const float*)d_in[2];
    const float* b1 = (const float*)d_in[3];
    const float* W2 = (const float*)d_in[4];
    const float* b2 = (const float*)d_in[5];
    float* out = (float*)d_out;

    const int N = in_sizes[0] / NF;   // 50000
    const int E = in_sizes[1] / 2;    // 1600000
    const int* src = ei;
    const int* dst = ei + E;

    // workspace layout (~38 MB); every consumed cell rewritten per call.
    unsigned*       h1T    = (unsigned*)d_ws;                  // N*64 u32 (12.8 MB, 4 slabs)
    unsigned*       aggT   = h1T + (size_t)N * 64;             // N*64 u32 (12.8 MB, 4 slabs)
    unsigned*       h2sb   = aggT + (size_t)N * 64;            // N*8  u32 (1.6 MB)
    float*          dis    = (float*)(h2sb + (size_t)N * 8);   // N
    int*            rowptr = (int*)(dis + N);                  // N+1
    int*            hist   = rowptr + N + 1;                   // NBLK*NB (0.8 MB)
    int*            bsum   = hist + NBLK * NB;                 // NB
    int*            bbase  = bsum + NB;                        // NB+1
    unsigned*       ebuf   = (unsigned*)(bbase + NB + 1);      // E u32 (6.4 MB)
    unsigned short* colidx = (unsigned short*)(ebuf + E);      // E u16 (3.2 MB)
    // W1T (64KB) overlays ebuf: ebuf is dead after passC, W1T written after.
    unsigned short* W1T    = (unsigned short*)ebuf;

    passA_kernel<<<NBLK, 256, 0, stream>>>(dst, hist, E);
    scanR_kernel<<<NB, NBLK, 0, stream>>>(hist, bsum);
    scanB_kernel<<<1, 512, 0, stream>>>(bsum, bbase, rowptr, N, E);
    scanC_kernel<<<NB, NBLK, 0, stream>>>(hist, bbase);
    passB_kernel<<<NBLK, 256, 0, stream>>>(src, dst, hist, ebuf, E);
    passC_kernel<<<NB, 256, 0, stream>>>(ebuf, bbase, rowptr, dis, colidx, N);

    w1t_kernel<<<128, 256, 0, stream>>>(W1, W1T);

    gemm1_mfma_kernel<<<(N + 63) / 64, 256, 0, stream>>>(x, W1T, dis,
                                                         (unsigned short*)h1T, N);

    for (int p = 0; p < 4; ++p)
        aggpass_kernel<<<(N + 15) / 16, 256, 0, stream>>>(rowptr, colidx, h1T, aggT, N, p);

    relu_gemm2_kernel<<<(N + 3) / 4, 256, 0, stream>>>(aggT, dis, b1, W2, h2sb, N);

    layer2_kernel<<<((size_t)N * 8 + 255) / 256, 256, 0, stream>>>(rowptr, colidx, h2sb, dis, b2, out, N);
}

// Round 12
// 190.931 us; speedup vs baseline: 1.0967x; 1.0330x over previous
//
#include <hip/hip_runtime.h>
#include <math.h>

#define NF 256
#define NH 128
#define NC 16
#define NB 391      // buckets of 128 nodes: 391*128 = 50048 >= 50000
#define NBLK 512    // binning blocks (passA/passB grid; scanR/scanC block dim)

typedef __attribute__((ext_vector_type(8))) short bf16x8;
typedef __attribute__((ext_vector_type(4))) float f32x4;

// ---- bf16 helpers ---------------------------------------------------------
__device__ __forceinline__ unsigned f2b(float f) {            // RNE to bf16 bits
    unsigned u = __float_as_uint(f);
    return (u + 0x7FFFu + ((u >> 16) & 1u)) >> 16;
}
__device__ __forceinline__ unsigned pack2(float a, float b) { // RNE pair
    return f2b(a) | (f2b(b) << 16);
}
__device__ __forceinline__ unsigned packt(float a, float b) { // truncate pair (MFMA inputs)
    return (__float_as_uint(a) >> 16) | (__float_as_uint(b) & 0xFFFF0000u);
}
__device__ __forceinline__ float blo(unsigned u) { return __uint_as_float(u << 16); }
__device__ __forceinline__ float bhi(unsigned u) { return __uint_as_float(u & 0xFFFF0000u); }

// ---------------------------------------------------------------------------
// passA: per-block bucket histogram (LDS atomics only; coalesced row write).
__global__ void passA_kernel(const int* __restrict__ dst, int* __restrict__ hist, int E) {
    __shared__ int h[NB];
    for (int i = threadIdx.x; i < NB; i += 256) h[i] = 0;
    __syncthreads();
    int b = blockIdx.x;
    int e0 = (int)((long long)b * E / NBLK), e1 = (int)((long long)(b + 1) * E / NBLK);
    for (int e = e0 + (int)threadIdx.x; e < e1; e += 256)
        atomicAdd(&h[dst[e] >> 7], 1);
    __syncthreads();
    for (int i = threadIdx.x; i < NB; i += 256) hist[b * NB + i] = h[i];
}

// scanR: bucketsum[k] = sum over blocks of hist[b][k].  (NBLK threads)
__global__ void scanR_kernel(const int* __restrict__ hist, int* __restrict__ bsum) {
    __shared__ int sm[NBLK];
    int k = blockIdx.x, t = threadIdx.x;
    sm[t] = hist[t * NB + k];
    __syncthreads();
    for (int off = NBLK / 2; off > 0; off >>= 1) {
        if (t < off) sm[t] += sm[t + off];
        __syncthreads();
    }
    if (t == 0) bsum[k] = sm[0];
}

// scanB: exclusive scan of NB bucket sums -> bbase[NB+1]; rowptr[N]=E.
__global__ void scanB_kernel(const int* __restrict__ bsum, int* __restrict__ bbase,
                             int* __restrict__ rowptr, int N, int E) {
    __shared__ int sm[512];
    int t = threadIdx.x;
    int v = (t < NB) ? bsum[t] : 0;
    sm[t] = v;
    __syncthreads();
    for (int off = 1; off < 512; off <<= 1) {
        int u = (t >= off) ? sm[t - off] : 0;
        __syncthreads();
        sm[t] += u;
        __syncthreads();
    }
    if (t < NB) bbase[t] = sm[t] - v;
    if (t == 0) { bbase[NB] = E; rowptr[N] = E; }
}

// scanC: per-bucket column exclusive scan across blocks + bucket base
// (overwrites hist with each block's exact output offset).  (NBLK threads)
__global__ void scanC_kernel(int* __restrict__ hist, const int* __restrict__ bbase) {
    __shared__ int sm[NBLK];
    int k = blockIdx.x, t = threadIdx.x;
    int v = hist[t * NB + k];
    sm[t] = v;
    __syncthreads();
    for (int off = 1; off < NBLK; off <<= 1) {
        int u = (t >= off) ? sm[t - off] : 0;
        __syncthreads();
        sm[t] += u;
        __syncthreads();
    }
    hist[t * NB + k] = bbase[k] + sm[t] - v;
}

// passB: binned scatter to bucket-sorted edge words. LDS cursors hold GLOBAL
// slots (disjoint per block, exact) -> deterministic ranges, contiguous runs.
__global__ void passB_kernel(const int* __restrict__ src, const int* __restrict__ dst,
                             const int* __restrict__ hist, unsigned* __restrict__ ebuf,
                             int E) {
    __shared__ int cur[NB];
    int b = blockIdx.x;
    for (int i = threadIdx.x; i < NB; i += 256) cur[i] = hist[b * NB + i];
    __syncthreads();
    int e0 = (int)((long long)b * E / NBLK), e1 = (int)((long long)(b + 1) * E / NBLK);
    for (int e = e0 + (int)threadIdx.x; e < e1; e += 256) {
        int d = dst[e];
        int pos = atomicAdd(&cur[d >> 7], 1);
        ebuf[pos] = ((unsigned)d << 16) | (unsigned)src[e];
    }
}

// passC: one block per bucket: per-node histogram -> rowptr/dis, then in-bucket
// scatter to final dst-sorted u16 colidx (8KB window, L2-hot).
__global__ void passC_kernel(const unsigned* __restrict__ ebuf, const int* __restrict__ bbase,
                             int* __restrict__ rowptr, float* __restrict__ dis,
                             unsigned short* __restrict__ colidx, int N) {
    __shared__ int h[128];
    __shared__ int s2[128];
    __shared__ int curp[128];
    int k = blockIdx.x, t = threadIdx.x;
    if (t < 128) h[t] = 0;
    __syncthreads();
    int e0 = bbase[k], e1 = bbase[k + 1];
    for (int e = e0 + t; e < e1; e += 256)
        atomicAdd(&h[(ebuf[e] >> 16) & 127], 1);
    __syncthreads();
    int v = (t < 128) ? h[t] : 0;
    if (t < 128) s2[t] = v;
    __syncthreads();
    for (int off = 1; off < 128; off <<= 1) {
        int u = (t < 128 && t >= off) ? s2[t - off] : 0;
        __syncthreads();
        if (t < 128) s2[t] += u;
        __syncthreads();
    }
    if (t < 128) {
        int node = k * 128 + t;
        int r = e0 + s2[t] - v;             // exclusive prefix -> first slot of node
        if (node < N) {
            rowptr[node] = r;
            dis[node] = rsqrtf((float)(v + 1));
        }
        curp[t] = r;
    }
    __syncthreads();
    for (int e = e0 + t; e < e1; e += 256) {
        unsigned w = ebuf[e];
        int dl = (w >> 16) & 127;
        int pos = atomicAdd(&curp[dl], 1);
        colidx[pos] = (unsigned short)(w & 0xFFFFu);
    }
}

// ---------------------------------------------------------------------------
// W1T[n][k] = bf16(W1[k][n]).  128x256 u16 (64KB) -> L2-resident B operand.
__global__ void w1t_kernel(const float* __restrict__ W1, unsigned short* __restrict__ W1T) {
    int idx = blockIdx.x * 256 + threadIdx.x;   // 128 blocks x 256 = 32768
    int n = idx >> 8, k = idx & 255;
    W1T[n * 256 + k] = (unsigned short)f2b(W1[(size_t)k * NH + n]);
}

// ---------------------------------------------------------------------------
// h1 = dis * (x @ W1) via MFMA bf16, no LDS.  ILP-forced structure:
// (1) ALL 16 x-loads issue up front; packed A lives in 32 VGPR.
// (2) Per nt-tile, the 8 B-fragments load as a batch before the 8 MFMAs ->
//     compiler pipelines nt+1's loads under nt's MFMAs (fixes the round-11
//     latency serialization: MfmaUtil 2.4%/VALUBusy 4%/dur 43us flatline).
// Stored SLAB-MAJOR: slab p holds cols [32p,32p+32) as h1T[p][node][32 u16].
__global__ __launch_bounds__(256) void gemm1_mfma_kernel(
    const float* __restrict__ x, const unsigned short* __restrict__ W1T,
    const float* __restrict__ dis, unsigned short* __restrict__ h1us, int N) {
    int tid = threadIdx.x;
    int wid = tid >> 6, lane = tid & 63;
    int lrow = lane & 15, lk = lane >> 4;      // A-frag: row=lane&15, k-chunk=lane>>4
    int rb = blockIdx.x * 64 + wid * 16;
    int ra = rb + lrow;
    int rc = ra < N ? ra : N - 1;              // clamp (last block); extras discarded
    const float* xr = x + (size_t)rc * NF + lk * 8;

    // hoist + pack the full A row-slice: 16 independent dwordx4 loads in flight
    bf16x8 a[8];
#pragma unroll
    for (int kk = 0; kk < 8; ++kk) {
        float4 lo = *reinterpret_cast<const float4*>(xr + kk * 32);
        float4 hi = *reinterpret_cast<const float4*>(xr + kk * 32 + 4);
        union { unsigned u[4]; bf16x8 v; } av;
        av.u[0] = packt(lo.x, lo.y);
        av.u[1] = packt(lo.z, lo.w);
        av.u[2] = packt(hi.x, hi.y);
        av.u[3] = packt(hi.z, hi.w);
        a[kk] = av.v;
    }

    f32x4 acc[8];
#pragma unroll
    for (int t = 0; t < 8; ++t) acc[t] = (f32x4){0.f, 0.f, 0.f, 0.f};

    const unsigned short* wbase = W1T + (size_t)lrow * 256 + lk * 8;
#pragma unroll
    for (int nt = 0; nt < 8; ++nt) {
        const unsigned short* wp = wbase + (size_t)nt * 16 * 256;  // n = nt*16+lrow
        bf16x8 b0 = *(const bf16x8*)(wp + 0 * 32);
        bf16x8 b1 = *(const bf16x8*)(wp + 1 * 32);
        bf16x8 b2 = *(const bf16x8*)(wp + 2 * 32);
        bf16x8 b3 = *(const bf16x8*)(wp + 3 * 32);
        bf16x8 b4 = *(const bf16x8*)(wp + 4 * 32);
        bf16x8 b5 = *(const bf16x8*)(wp + 5 * 32);
        bf16x8 b6 = *(const bf16x8*)(wp + 6 * 32);
        bf16x8 b7 = *(const bf16x8*)(wp + 7 * 32);
        acc[nt] = __builtin_amdgcn_mfma_f32_16x16x32_bf16(a[0], b0, acc[nt], 0, 0, 0);
        acc[nt] = __builtin_amdgcn_mfma_f32_16x16x32_bf16(a[1], b1, acc[nt], 0, 0, 0);
        acc[nt] = __builtin_amdgcn_mfma_f32_16x16x32_bf16(a[2], b2, acc[nt], 0, 0, 0);
        acc[nt] = __builtin_amdgcn_mfma_f32_16x16x32_bf16(a[3], b3, acc[nt], 0, 0, 0);
        acc[nt] = __builtin_amdgcn_mfma_f32_16x16x32_bf16(a[4], b4, acc[nt], 0, 0, 0);
        acc[nt] = __builtin_amdgcn_mfma_f32_16x16x32_bf16(a[5], b5, acc[nt], 0, 0, 0);
        acc[nt] = __builtin_amdgcn_mfma_f32_16x16x32_bf16(a[6], b6, acc[nt], 0, 0, 0);
        acc[nt] = __builtin_amdgcn_mfma_f32_16x16x32_bf16(a[7], b7, acc[nt], 0, 0, 0);
    }

    // C/D layout (verified m89): col = lane&15, row_in_tile = (lane>>4)*4 + r
    int crow0 = rb + lk * 4;
#pragma unroll
    for (int r = 0; r < 4; ++r) {
        int row = crow0 + r;
        if (row < N) {
            float dr = dis[row];
#pragma unroll
            for (int nt = 0; nt < 8; ++nt) {
                size_t ad = ((size_t)(nt >> 1) * N + row) * 32 + ((nt & 1) * 16 + lrow);
                h1us[ad] = (unsigned short)f2b(acc[nt][r] * dr);
            }
        }
    }
}

// ---------------------------------------------------------------------------
// Agg pass p: sum self + neighbors over slab p (32 features, 16 u32/node).
// 16 lanes/node; all CUs gather from the SAME 3.2MB slab (per-XCD-L2
// resident).  Unroll-8: 8 independent gathers in flight (latency-bound).
__global__ __launch_bounds__(256) void aggpass_kernel(
    const int* __restrict__ rowptr, const unsigned short* __restrict__ colidx,
    const unsigned* __restrict__ h1T, unsigned* __restrict__ aggT, int N, int p) {
    int i = blockIdx.x * 16 + (threadIdx.x >> 4);
    if (i >= N) return;
    int l = threadIdx.x & 15;
    const unsigned* slab = h1T + (size_t)p * N * 16;
    unsigned sv = slab[(size_t)i * 16 + l];             // self-loop
    float ax = blo(sv), ay = bhi(sv);
    int e = rowptr[i], e1 = rowptr[i + 1];
    for (; e + 8 <= e1; e += 8) {
        int a0 = colidx[e],     a1 = colidx[e + 1], a2 = colidx[e + 2], a3 = colidx[e + 3];
        int a4 = colidx[e + 4], a5 = colidx[e + 5], a6 = colidx[e + 6], a7 = colidx[e + 7];
        unsigned v0 = slab[(size_t)a0 * 16 + l];
        unsigned v1 = slab[(size_t)a1 * 16 + l];
        unsigned v2 = slab[(size_t)a2 * 16 + l];
        unsigned v3 = slab[(size_t)a3 * 16 + l];
        unsigned v4 = slab[(size_t)a4 * 16 + l];
        unsigned v5 = slab[(size_t)a5 * 16 + l];
        unsigned v6 = slab[(size_t)a6 * 16 + l];
        unsigned v7 = slab[(size_t)a7 * 16 + l];
        ax += ((blo(v0) + blo(v1)) + (blo(v2) + blo(v3)))
            + ((blo(v4) + blo(v5)) + (blo(v6) + blo(v7)));
        ay += ((bhi(v0) + bhi(v1)) + (bhi(v2) + bhi(v3)))
            + ((bhi(v4) + bhi(v5)) + (bhi(v6) + bhi(v7)));
    }
    for (; e + 4 <= e1; e += 4) {
        int a0 = colidx[e], a1 = colidx[e + 1], a2 = colidx[e + 2], a3 = colidx[e + 3];
        unsigned v0 = slab[(size_t)a0 * 16 + l];
        unsigned v1 = slab[(size_t)a1 * 16 + l];
        unsigned v2 = slab[(size_t)a2 * 16 + l];
        unsigned v3 = slab[(size_t)a3 * 16 + l];
        ax += (blo(v0) + blo(v1)) + (blo(v2) + blo(v3));
        ay += (bhi(v0) + bhi(v1)) + (bhi(v2) + bhi(v3));
    }
    for (; e < e1; ++e) {
        unsigned v = slab[(size_t)colidx[e] * 16 + l];
        ax += blo(v); ay += bhi(v);
    }
    aggT[(size_t)p * N * 16 + (size_t)i * 16 + l] = pack2(ax, ay);
}

// ---------------------------------------------------------------------------
// ReLU + bias + GEMM2 from aggT.  One wave per node (4 nodes/block).
// Lane l: slab p=l>>4, u32 (l&15) -> cols c0 = 32p + 2*(l&15), c0+1.
__global__ __launch_bounds__(256) void relu_gemm2_kernel(
    const unsigned* __restrict__ aggT, const float* __restrict__ dis,
    const float* __restrict__ b1, const float* __restrict__ W2,
    unsigned* __restrict__ h2sb, int N) {
    __shared__ float sW2[NH * NC];   // 8 KB
    __shared__ float srow[4][NH];    // 2 KB
    int tid = threadIdx.x;
    for (int k = tid; k < NH * NC; k += 256) sW2[k] = W2[k];
    __syncthreads();

    int wid = tid >> 6, lane = tid & 63;
    int i = blockIdx.x * 4 + wid;
    if (i >= N) return;
    int p = lane >> 4, l16 = lane & 15;
    unsigned v = aggT[((size_t)p * N + i) * 16 + l16];
    float di = dis[i];
    int c0 = p * 32 + l16 * 2;
    srow[wid][c0]     = fmaxf(di * blo(v) + b1[c0], 0.f);
    srow[wid][c0 + 1] = fmaxf(di * bhi(v) + b1[c0 + 1], 0.f);
    int j = lane & 15, q = lane >> 4;
    const float* rw = srow[wid];
    float pacc = 0.f;
#pragma unroll
    for (int cc = 0; cc < 32; ++cc) {
        int c = q * 32 + cc;
        pacc += rw[c] * sW2[c * NC + j];
    }
    pacc += __shfl_xor(pacc, 16, 64);
    pacc += __shfl_xor(pacc, 32, 64);
    float dp = di * pacc;
    float plo = __shfl(dp, (lane << 1) & 63, 64);
    float phi = __shfl(dp, ((lane << 1) | 1) & 63, 64);
    if (lane < 8) h2sb[(size_t)i * 8 + lane] = pack2(plo, phi);
}

// ---------------------------------------------------------------------------
// Layer 2 pull + bias + log_softmax.  8 lanes/node (2 classes per lane).
// h2sb is 1.6MB -> already per-XCD-L2-resident.
__global__ void layer2_kernel(const int* __restrict__ rowptr, const unsigned short* __restrict__ colidx,
                              const unsigned* __restrict__ h2sb, const float* __restrict__ dis,
                              const float* __restrict__ b2, float* __restrict__ out, int N) {
    int t = blockIdx.x * 256 + threadIdx.x;
    int i = t >> 3;
    if (i >= N) return;
    int j2 = t & 7;
    int e = rowptr[i], e1 = rowptr[i + 1];
    unsigned sv = h2sb[(size_t)i * 8 + j2];             // self-loop
    float ax = blo(sv), ay = bhi(sv);
    for (; e + 4 <= e1; e += 4) {
        int a = colidx[e], b = colidx[e + 1], c = colidx[e + 2], d = colidx[e + 3];
        unsigned ga = h2sb[(size_t)a * 8 + j2];
        unsigned gb = h2sb[(size_t)b * 8 + j2];
        unsigned gc = h2sb[(size_t)c * 8 + j2];
        unsigned gd = h2sb[(size_t)d * 8 + j2];
        ax += (blo(ga) + blo(gb)) + (blo(gc) + blo(gd));
        ay += (bhi(ga) + bhi(gb)) + (bhi(gc) + bhi(gd));
    }
    for (; e < e1; ++e) {
        unsigned g = h2sb[(size_t)colidx[e] * 8 + j2];
        ax += blo(g); ay += bhi(g);
    }
    float di = dis[i];
    float l0 = di * ax + b2[2 * j2];
    float l1 = di * ay + b2[2 * j2 + 1];
    float m = fmaxf(l0, l1);
    m = fmaxf(m, __shfl_xor(m, 1, 64));
    m = fmaxf(m, __shfl_xor(m, 2, 64));
    m = fmaxf(m, __shfl_xor(m, 4, 64));
    float s = __expf(l0 - m) + __expf(l1 - m);
    s += __shfl_xor(s, 1, 64);
    s += __shfl_xor(s, 2, 64);
    s += __shfl_xor(s, 4, 64);
    float lse = m + __logf(s);
    float2 o = make_float2(l0 - lse, l1 - lse);
    *reinterpret_cast<float2*>(out + (size_t)i * NC + 2 * j2) = o;
}

// ---------------------------------------------------------------------------
extern "C" void kernel_launch(void* const* d_in, const int* in_sizes, int n_in,
                              void* d_out, int out_size, void* d_ws, size_t ws_size,
                              hipStream_t stream) {
    const float* x  = (const float*)d_in[0];
    const int*   ei = (const int*)d_in[1];
    const float* W1 = (const float*)d_in[2];
    const float* b1 = (const float*)d_in[3];
    const float* W2 = (const float*)d_in[4];
    const float* b2 = (const float*)d_in[5];
    float* out = (float*)d_out;

    const int N = in_sizes[0] / NF;   // 50000
    const int E = in_sizes[1] / 2;    // 1600000
    const int* src = ei;
    const int* dst = ei + E;

    // workspace layout (~38 MB); every consumed cell rewritten per call.
    unsigned*       h1T    = (unsigned*)d_ws;                  // N*64 u32 (12.8 MB, 4 slabs)
    unsigned*       aggT   = h1T + (size_t)N * 64;             // N*64 u32 (12.8 MB, 4 slabs)
    unsigned*       h2sb   = aggT + (size_t)N * 64;            // N*8  u32 (1.6 MB)
    float*          dis    = (float*)(h2sb + (size_t)N * 8);   // N
    int*            rowptr = (int*)(dis + N);                  // N+1
    int*            hist   = rowptr + N + 1;                   // NBLK*NB (0.8 MB)
    int*            bsum   = hist + NBLK * NB;                 // NB
    int*            bbase  = bsum + NB;                        // NB+1
    unsigned*       ebuf   = (unsigned*)(bbase + NB + 1);      // E u32 (6.4 MB)
    unsigned short* colidx = (unsigned short*)(ebuf + E);      // E u16 (3.2 MB)
    // W1T (64KB) overlays ebuf: ebuf is dead after passC, W1T written after.
    unsigned short* W1T    = (unsigned short*)ebuf;

    passA_kernel<<<NBLK, 256, 0, stream>>>(dst, hist, E);
    scanR_kernel<<<NB, NBLK, 0, stream>>>(hist, bsum);
    scanB_kernel<<<1, 512, 0, stream>>>(bsum, bbase, rowptr, N, E);
    scanC_kernel<<<NB, NBLK, 0, stream>>>(hist, bbase);
    passB_kernel<<<NBLK, 256, 0, stream>>>(src, dst, hist, ebuf, E);
    passC_kernel<<<NB, 256, 0, stream>>>(ebuf, bbase, rowptr, dis, colidx, N);

    w1t_kernel<<<128, 256, 0, stream>>>(W1, W1T);

    gemm1_mfma_kernel<<<(N + 63) / 64, 256, 0, stream>>>(x, W1T, dis,
                                                         (unsigned short*)h1T, N);

    for (int p = 0; p < 4; ++p)
        aggpass_kernel<<<(N + 15) / 16, 256, 0, stream>>>(rowptr, colidx, h1T, aggT, N, p);

    relu_gemm2_kernel<<<(N + 3) / 4, 256, 0, stream>>>(aggT, dis, b1, W2, h2sb, N);

    layer2_kernel<<<((size_t)N * 8 + 255) / 256, 256, 0, stream>>>(rowptr, colidx, h2sb, dis, b2, out, N);
}

// Round 13
// 177.585 us; speedup vs baseline: 1.1791x; 1.0752x over previous
//
#include <hip/hip_runtime.h>
#include <math.h>

#define NF 256
#define NH 128
#define NC 16
#define NB 391      // buckets of 128 nodes: 391*128 = 50048 >= 50000
#define NBLK 512    // binning blocks (passA/passB grid; scanR/scanC block dim)

typedef __attribute__((ext_vector_type(8))) short bf16x8;
typedef __attribute__((ext_vector_type(4))) float f32x4;

// ---- bf16 helpers ---------------------------------------------------------
__device__ __forceinline__ unsigned f2b(float f) {            // RNE to bf16 bits
    unsigned u = __float_as_uint(f);
    return (u + 0x7FFFu + ((u >> 16) & 1u)) >> 16;
}
__device__ __forceinline__ unsigned pack2(float a, float b) { // RNE pair
    return f2b(a) | (f2b(b) << 16);
}
__device__ __forceinline__ unsigned packt(float a, float b) { // truncate pair (MFMA inputs)
    return (__float_as_uint(a) >> 16) | (__float_as_uint(b) & 0xFFFF0000u);
}
__device__ __forceinline__ float blo(unsigned u) { return __uint_as_float(u << 16); }
__device__ __forceinline__ float bhi(unsigned u) { return __uint_as_float(u & 0xFFFF0000u); }

// ---------------------------------------------------------------------------
// passA: per-block bucket histogram (LDS atomics only; coalesced row write).
__global__ void passA_kernel(const int* __restrict__ dst, int* __restrict__ hist, int E) {
    __shared__ int h[NB];
    for (int i = threadIdx.x; i < NB; i += 256) h[i] = 0;
    __syncthreads();
    int b = blockIdx.x;
    int e0 = (int)((long long)b * E / NBLK), e1 = (int)((long long)(b + 1) * E / NBLK);
    for (int e = e0 + (int)threadIdx.x; e < e1; e += 256)
        atomicAdd(&h[dst[e] >> 7], 1);
    __syncthreads();
    for (int i = threadIdx.x; i < NB; i += 256) hist[b * NB + i] = h[i];
}

// scanR: bucketsum[k] = sum over blocks of hist[b][k].  (NBLK threads)
__global__ void scanR_kernel(const int* __restrict__ hist, int* __restrict__ bsum) {
    __shared__ int sm[NBLK];
    int k = blockIdx.x, t = threadIdx.x;
    sm[t] = hist[t * NB + k];
    __syncthreads();
    for (int off = NBLK / 2; off > 0; off >>= 1) {
        if (t < off) sm[t] += sm[t + off];
        __syncthreads();
    }
    if (t == 0) bsum[k] = sm[0];
}

// scanB: exclusive scan of NB bucket sums -> bbase[NB+1]; rowptr[N]=E.
__global__ void scanB_kernel(const int* __restrict__ bsum, int* __restrict__ bbase,
                             int* __restrict__ rowptr, int N, int E) {
    __shared__ int sm[512];
    int t = threadIdx.x;
    int v = (t < NB) ? bsum[t] : 0;
    sm[t] = v;
    __syncthreads();
    for (int off = 1; off < 512; off <<= 1) {
        int u = (t >= off) ? sm[t - off] : 0;
        __syncthreads();
        sm[t] += u;
        __syncthreads();
    }
    if (t < NB) bbase[t] = sm[t] - v;
    if (t == 0) { bbase[NB] = E; rowptr[N] = E; }
}

// scanC: per-bucket column exclusive scan across blocks + bucket base
// (overwrites hist with each block's exact output offset).  (NBLK threads)
__global__ void scanC_kernel(int* __restrict__ hist, const int* __restrict__ bbase) {
    __shared__ int sm[NBLK];
    int k = blockIdx.x, t = threadIdx.x;
    int v = hist[t * NB + k];
    sm[t] = v;
    __syncthreads();
    for (int off = 1; off < NBLK; off <<= 1) {
        int u = (t >= off) ? sm[t - off] : 0;
        __syncthreads();
        sm[t] += u;
        __syncthreads();
    }
    hist[t * NB + k] = bbase[k] + sm[t] - v;
}

// passB: binned scatter to bucket-sorted edge words. LDS cursors hold GLOBAL
// slots (disjoint per block, exact) -> deterministic ranges, contiguous runs.
__global__ void passB_kernel(const int* __restrict__ src, const int* __restrict__ dst,
                             const int* __restrict__ hist, unsigned* __restrict__ ebuf,
                             int E) {
    __shared__ int cur[NB];
    int b = blockIdx.x;
    for (int i = threadIdx.x; i < NB; i += 256) cur[i] = hist[b * NB + i];
    __syncthreads();
    int e0 = (int)((long long)b * E / NBLK), e1 = (int)((long long)(b + 1) * E / NBLK);
    for (int e = e0 + (int)threadIdx.x; e < e1; e += 256) {
        int d = dst[e];
        int pos = atomicAdd(&cur[d >> 7], 1);
        ebuf[pos] = ((unsigned)d << 16) | (unsigned)src[e];
    }
}

// passC: one block per bucket: per-node histogram -> rowptr/dis, then in-bucket
// scatter to final dst-sorted u16 colidx (8KB window, L2-hot).
__global__ void passC_kernel(const unsigned* __restrict__ ebuf, const int* __restrict__ bbase,
                             int* __restrict__ rowptr, float* __restrict__ dis,
                             unsigned short* __restrict__ colidx, int N) {
    __shared__ int h[128];
    __shared__ int s2[128];
    __shared__ int curp[128];
    int k = blockIdx.x, t = threadIdx.x;
    if (t < 128) h[t] = 0;
    __syncthreads();
    int e0 = bbase[k], e1 = bbase[k + 1];
    for (int e = e0 + t; e < e1; e += 256)
        atomicAdd(&h[(ebuf[e] >> 16) & 127], 1);
    __syncthreads();
    int v = (t < 128) ? h[t] : 0;
    if (t < 128) s2[t] = v;
    __syncthreads();
    for (int off = 1; off < 128; off <<= 1) {
        int u = (t < 128 && t >= off) ? s2[t - off] : 0;
        __syncthreads();
        if (t < 128) s2[t] += u;
        __syncthreads();
    }
    if (t < 128) {
        int node = k * 128 + t;
        int r = e0 + s2[t] - v;             // exclusive prefix -> first slot of node
        if (node < N) {
            rowptr[node] = r;
            dis[node] = rsqrtf((float)(v + 1));
        }
        curp[t] = r;
    }
    __syncthreads();
    for (int e = e0 + t; e < e1; e += 256) {
        unsigned w = ebuf[e];
        int dl = (w >> 16) & 127;
        int pos = atomicAdd(&curp[dl], 1);
        colidx[pos] = (unsigned short)(w & 0xFFFFu);
    }
}

// ---------------------------------------------------------------------------
// W1T[n][k] = bf16(W1[k][n]).  128x256 u16 (64KB) -> L2-resident B operand.
__global__ void w1t_kernel(const float* __restrict__ W1, unsigned short* __restrict__ W1T) {
    int idx = blockIdx.x * 256 + threadIdx.x;   // 128 blocks x 256 = 32768
    int n = idx >> 8, k = idx & 255;
    W1T[n * 256 + k] = (unsigned short)f2b(W1[(size_t)k * NH + n]);
}

// ---------------------------------------------------------------------------
// h1 = dis * (x @ W1) via MFMA bf16, no LDS.  __launch_bounds__(256,3):
// grid is 782 blocks = 3.05 blocks/CU, so 3 resident blocks is all we can
// use; this raises the VGPR budget to ~170 so the hoisted A block (32 VGPR)
// + acc (32) + batched B-fragments stay LIVE and loads pipeline.  (Round-12
// failure: default allocator capped at 52 VGPR -> fully serialized loads,
// 425 cy/load, MfmaUtil 2.4%.)
__global__ __launch_bounds__(256, 3) void gemm1_mfma_kernel(
    const float* __restrict__ x, const unsigned short* __restrict__ W1T,
    const float* __restrict__ dis, unsigned short* __restrict__ h1us, int N) {
    int tid = threadIdx.x;
    int wid = tid >> 6, lane = tid & 63;
    int lrow = lane & 15, lk = lane >> 4;      // A-frag: row=lane&15, k-chunk=lane>>4
    int rb = blockIdx.x * 64 + wid * 16;
    int ra = rb + lrow;
    int rc = ra < N ? ra : N - 1;              // clamp (last block); extras discarded
    const float* xr = x + (size_t)rc * NF + lk * 8;

    // hoist + pack the full A row-slice: 16 independent dwordx4 loads in flight
    bf16x8 a[8];
#pragma unroll
    for (int kk = 0; kk < 8; ++kk) {
        float4 lo = *reinterpret_cast<const float4*>(xr + kk * 32);
        float4 hi = *reinterpret_cast<const float4*>(xr + kk * 32 + 4);
        union { unsigned u[4]; bf16x8 v; } av;
        av.u[0] = packt(lo.x, lo.y);
        av.u[1] = packt(lo.z, lo.w);
        av.u[2] = packt(hi.x, hi.y);
        av.u[3] = packt(hi.z, hi.w);
        a[kk] = av.v;
    }

    f32x4 acc[8];
#pragma unroll
    for (int t = 0; t < 8; ++t) acc[t] = (f32x4){0.f, 0.f, 0.f, 0.f};

    const unsigned short* wbase = W1T + (size_t)lrow * 256 + lk * 8;
#pragma unroll
    for (int nt = 0; nt < 8; ++nt) {
        const unsigned short* wp = wbase + (size_t)nt * 16 * 256;  // n = nt*16+lrow
        bf16x8 b0 = *(const bf16x8*)(wp + 0 * 32);
        bf16x8 b1 = *(const bf16x8*)(wp + 1 * 32);
        bf16x8 b2 = *(const bf16x8*)(wp + 2 * 32);
        bf16x8 b3 = *(const bf16x8*)(wp + 3 * 32);
        bf16x8 b4 = *(const bf16x8*)(wp + 4 * 32);
        bf16x8 b5 = *(const bf16x8*)(wp + 5 * 32);
        bf16x8 b6 = *(const bf16x8*)(wp + 6 * 32);
        bf16x8 b7 = *(const bf16x8*)(wp + 7 * 32);
        acc[nt] = __builtin_amdgcn_mfma_f32_16x16x32_bf16(a[0], b0, acc[nt], 0, 0, 0);
        acc[nt] = __builtin_amdgcn_mfma_f32_16x16x32_bf16(a[1], b1, acc[nt], 0, 0, 0);
        acc[nt] = __builtin_amdgcn_mfma_f32_16x16x32_bf16(a[2], b2, acc[nt], 0, 0, 0);
        acc[nt] = __builtin_amdgcn_mfma_f32_16x16x32_bf16(a[3], b3, acc[nt], 0, 0, 0);
        acc[nt] = __builtin_amdgcn_mfma_f32_16x16x32_bf16(a[4], b4, acc[nt], 0, 0, 0);
        acc[nt] = __builtin_amdgcn_mfma_f32_16x16x32_bf16(a[5], b5, acc[nt], 0, 0, 0);
        acc[nt] = __builtin_amdgcn_mfma_f32_16x16x32_bf16(a[6], b6, acc[nt], 0, 0, 0);
        acc[nt] = __builtin_amdgcn_mfma_f32_16x16x32_bf16(a[7], b7, acc[nt], 0, 0, 0);
    }

    // C/D layout (verified m89): col = lane&15, row_in_tile = (lane>>4)*4 + r
    int crow0 = rb + lk * 4;
#pragma unroll
    for (int r = 0; r < 4; ++r) {
        int row = crow0 + r;
        if (row < N) {
            float dr = dis[row];
#pragma unroll
            for (int nt = 0; nt < 8; ++nt) {
                size_t ad = ((size_t)(nt >> 1) * N + row) * 32 + ((nt & 1) * 16 + lrow);
                h1us[ad] = (unsigned short)f2b(acc[nt][r] * dr);
            }
        }
    }
}

// ---------------------------------------------------------------------------
// All 4 agg passes in ONE dispatch: p = blockIdx.x / bps (blocks dispatch
// roughly in order -> temporal slab locality preserved; perf-only assumption).
// Per node, sum self + neighbors over slab p (32 features, 16 u32/node);
// 16 lanes/node; unroll-8 keeps 8 independent gathers in flight.
__global__ __launch_bounds__(256) void aggall_kernel(
    const int* __restrict__ rowptr, const unsigned short* __restrict__ colidx,
    const unsigned* __restrict__ h1T, unsigned* __restrict__ aggT, int N, int bps) {
    int p = blockIdx.x / bps;
    int i = (blockIdx.x - p * bps) * 16 + (threadIdx.x >> 4);
    if (i >= N) return;
    int l = threadIdx.x & 15;
    const unsigned* slab = h1T + (size_t)p * N * 16;
    unsigned sv = slab[(size_t)i * 16 + l];             // self-loop
    float ax = blo(sv), ay = bhi(sv);
    int e = rowptr[i], e1 = rowptr[i + 1];
    for (; e + 8 <= e1; e += 8) {
        int a0 = colidx[e],     a1 = colidx[e + 1], a2 = colidx[e + 2], a3 = colidx[e + 3];
        int a4 = colidx[e + 4], a5 = colidx[e + 5], a6 = colidx[e + 6], a7 = colidx[e + 7];
        unsigned v0 = slab[(size_t)a0 * 16 + l];
        unsigned v1 = slab[(size_t)a1 * 16 + l];
        unsigned v2 = slab[(size_t)a2 * 16 + l];
        unsigned v3 = slab[(size_t)a3 * 16 + l];
        unsigned v4 = slab[(size_t)a4 * 16 + l];
        unsigned v5 = slab[(size_t)a5 * 16 + l];
        unsigned v6 = slab[(size_t)a6 * 16 + l];
        unsigned v7 = slab[(size_t)a7 * 16 + l];
        ax += ((blo(v0) + blo(v1)) + (blo(v2) + blo(v3)))
            + ((blo(v4) + blo(v5)) + (blo(v6) + blo(v7)));
        ay += ((bhi(v0) + bhi(v1)) + (bhi(v2) + bhi(v3)))
            + ((bhi(v4) + bhi(v5)) + (bhi(v6) + bhi(v7)));
    }
    for (; e + 4 <= e1; e += 4) {
        int a0 = colidx[e], a1 = colidx[e + 1], a2 = colidx[e + 2], a3 = colidx[e + 3];
        unsigned v0 = slab[(size_t)a0 * 16 + l];
        unsigned v1 = slab[(size_t)a1 * 16 + l];
        unsigned v2 = slab[(size_t)a2 * 16 + l];
        unsigned v3 = slab[(size_t)a3 * 16 + l];
        ax += (blo(v0) + blo(v1)) + (blo(v2) + blo(v3));
        ay += (bhi(v0) + bhi(v1)) + (bhi(v2) + bhi(v3));
    }
    for (; e < e1; ++e) {
        unsigned v = slab[(size_t)colidx[e] * 16 + l];
        ax += blo(v); ay += bhi(v);
    }
    aggT[(size_t)p * N * 16 + (size_t)i * 16 + l] = pack2(ax, ay);
}

// ---------------------------------------------------------------------------
// ReLU + bias + GEMM2 from aggT.  One wave per node (4 nodes/block).
// Lane l: slab p=l>>4, u32 (l&15) -> cols c0 = 32p + 2*(l&15), c0+1.
__global__ __launch_bounds__(256) void relu_gemm2_kernel(
    const unsigned* __restrict__ aggT, const float* __restrict__ dis,
    const float* __restrict__ b1, const float* __restrict__ W2,
    unsigned* __restrict__ h2sb, int N) {
    __shared__ float sW2[NH * NC];   // 8 KB
    __shared__ float srow[4][NH];    // 2 KB
    int tid = threadIdx.x;
    for (int k = tid; k < NH * NC; k += 256) sW2[k] = W2[k];
    __syncthreads();

    int wid = tid >> 6, lane = tid & 63;
    int i = blockIdx.x * 4 + wid;
    if (i >= N) return;
    int p = lane >> 4, l16 = lane & 15;
    unsigned v = aggT[((size_t)p * N + i) * 16 + l16];
    float di = dis[i];
    int c0 = p * 32 + l16 * 2;
    srow[wid][c0]     = fmaxf(di * blo(v) + b1[c0], 0.f);
    srow[wid][c0 + 1] = fmaxf(di * bhi(v) + b1[c0 + 1], 0.f);
    int j = lane & 15, q = lane >> 4;
    const float* rw = srow[wid];
    float pacc = 0.f;
#pragma unroll
    for (int cc = 0; cc < 32; ++cc) {
        int c = q * 32 + cc;
        pacc += rw[c] * sW2[c * NC + j];
    }
    pacc += __shfl_xor(pacc, 16, 64);
    pacc += __shfl_xor(pacc, 32, 64);
    float dp = di * pacc;
    float plo = __shfl(dp, (lane << 1) & 63, 64);
    float phi = __shfl(dp, ((lane << 1) | 1) & 63, 64);
    if (lane < 8) h2sb[(size_t)i * 8 + lane] = pack2(plo, phi);
}

// ---------------------------------------------------------------------------
// Layer 2 pull + bias + log_softmax.  8 lanes/node (2 classes per lane).
// h2sb is 1.6MB -> already per-XCD-L2-resident.
__global__ void layer2_kernel(const int* __restrict__ rowptr, const unsigned short* __restrict__ colidx,
                              const unsigned* __restrict__ h2sb, const float* __restrict__ dis,
                              const float* __restrict__ b2, float* __restrict__ out, int N) {
    int t = blockIdx.x * 256 + threadIdx.x;
    int i = t >> 3;
    if (i >= N) return;
    int j2 = t & 7;
    int e = rowptr[i], e1 = rowptr[i + 1];
    unsigned sv = h2sb[(size_t)i * 8 + j2];             // self-loop
    float ax = blo(sv), ay = bhi(sv);
    for (; e + 4 <= e1; e += 4) {
        int a = colidx[e], b = colidx[e + 1], c = colidx[e + 2], d = colidx[e + 3];
        unsigned ga = h2sb[(size_t)a * 8 + j2];
        unsigned gb = h2sb[(size_t)b * 8 + j2];
        unsigned gc = h2sb[(size_t)c * 8 + j2];
        unsigned gd = h2sb[(size_t)d * 8 + j2];
        ax += (blo(ga) + blo(gb)) + (blo(gc) + blo(gd));
        ay += (bhi(ga) + bhi(gb)) + (bhi(gc) + bhi(gd));
    }
    for (; e < e1; ++e) {
        unsigned g = h2sb[(size_t)colidx[e] * 8 + j2];
        ax += blo(g); ay += bhi(g);
    }
    float di = dis[i];
    float l0 = di * ax + b2[2 * j2];
    float l1 = di * ay + b2[2 * j2 + 1];
    float m = fmaxf(l0, l1);
    m = fmaxf(m, __shfl_xor(m, 1, 64));
    m = fmaxf(m, __shfl_xor(m, 2, 64));
    m = fmaxf(m, __shfl_xor(m, 4, 64));
    float s = __expf(l0 - m) + __expf(l1 - m);
    s += __shfl_xor(s, 1, 64);
    s += __shfl_xor(s, 2, 64);
    s += __shfl_xor(s, 4, 64);
    float lse = m + __logf(s);
    float2 o = make_float2(l0 - lse, l1 - lse);
    *reinterpret_cast<float2*>(out + (size_t)i * NC + 2 * j2) = o;
}

// ---------------------------------------------------------------------------
extern "C" void kernel_launch(void* const* d_in, const int* in_sizes, int n_in,
                              void* d_out, int out_size, void* d_ws, size_t ws_size,
                              hipStream_t stream) {
    const float* x  = (const float*)d_in[0];
    const int*   ei = (const int*)d_in[1];
    const float* W1 = (const float*)d_in[2];
    const float* b1 = (const float*)d_in[3];
    const float* W2 = (const float*)d_in[4];
    const float* b2 = (const float*)d_in[5];
    float* out = (float*)d_out;

    const int N = in_sizes[0] / NF;   // 50000
    const int E = in_sizes[1] / 2;    // 1600000
    const int* src = ei;
    const int* dst = ei + E;

    // workspace layout (~38 MB); every consumed cell rewritten per call.
    unsigned*       h1T    = (unsigned*)d_ws;                  // N*64 u32 (12.8 MB, 4 slabs)
    unsigned*       aggT   = h1T + (size_t)N * 64;             // N*64 u32 (12.8 MB, 4 slabs)
    unsigned*       h2sb   = aggT + (size_t)N * 64;            // N*8  u32 (1.6 MB)
    float*          dis    = (float*)(h2sb + (size_t)N * 8);   // N
    int*            rowptr = (int*)(dis + N);                  // N+1
    int*            hist   = rowptr + N + 1;                   // NBLK*NB (0.8 MB)
    int*            bsum   = hist + NBLK * NB;                 // NB
    int*            bbase  = bsum + NB;                        // NB+1
    unsigned*       ebuf   = (unsigned*)(bbase + NB + 1);      // E u32 (6.4 MB)
    unsigned short* colidx = (unsigned short*)(ebuf + E);      // E u16 (3.2 MB)
    // W1T (64KB) overlays ebuf: ebuf is dead after passC, W1T written after.
    unsigned short* W1T    = (unsigned short*)ebuf;

    passA_kernel<<<NBLK, 256, 0, stream>>>(dst, hist, E);
    scanR_kernel<<<NB, NBLK, 0, stream>>>(hist, bsum);
    scanB_kernel<<<1, 512, 0, stream>>>(bsum, bbase, rowptr, N, E);
    scanC_kernel<<<NB, NBLK, 0, stream>>>(hist, bbase);
    passB_kernel<<<NBLK, 256, 0, stream>>>(src, dst, hist, ebuf, E);
    passC_kernel<<<NB, 256, 0, stream>>>(ebuf, bbase, rowptr, dis, colidx, N);

    w1t_kernel<<<128, 256, 0, stream>>>(W1, W1T);

    gemm1_mfma_kernel<<<(N + 63) / 64, 256, 0, stream>>>(x, W1T, dis,
                                                         (unsigned short*)h1T, N);

    const int bps = (N + 15) / 16;   // blocks per slab
    aggall_kernel<<<4 * bps, 256, 0, stream>>>(rowptr, colidx, h1T, aggT, N, bps);

    relu_gemm2_kernel<<<(N + 3) / 4, 256, 0, stream>>>(aggT, dis, b1, W2, h2sb, N);

    layer2_kernel<<<((size_t)N * 8 + 255) / 256, 256, 0, stream>>>(rowptr, colidx, h2sb, dis, b2, out, N);
}